// Round 3
// baseline (2012.990 us; speedup 1.0000x reference)
//
#include <hip/hip_runtime.h>
#include <math.h>

#define PI_D 3.14159265358979323846
#define TWO_PI_F 6.2831853071795864f

// ---------------- persistent device buffers ---------------------------------
__device__ __align__(16) float2  g_Mf [128*128];
__device__ __align__(16) float2  g_Mb [128*128];
__device__ __align__(16) float2  g_F  [128*128];
__device__ __align__(16) float2  g_IF [128*128];
__device__ __align__(16) float   g_x1 [4*48*16384];
__device__ __align__(16) float2  g_bufA[64*16384];
__device__ __align__(16) float   g_mag[64*16384];
__device__ __align__(16) float   g_pha[64*16384];
__device__ __align__(16) float   g_t1 [64*16384];
__device__ __align__(16) float   g_t2 [64*16384];
__device__ __align__(16) float   g_cat[4*48*16384];

// ---------------- matrix builders -------------------------------------------
__global__ void k_build_M05f() {
    int tid = blockIdx.x*blockDim.x + threadIdx.x;
    if (tid >= 128*128) return;
    int o = tid >> 7, m = tid & 127;
    const double chc = -PI_D/128.0 * tan(PI_D/8.0) * 0.25;
    const double c   =  PI_D/(512.0*sin(PI_D/4.0));
    const double inv2pi = 1.0/(2.0*PI_D);
    float sr, si;
    {   // q = 2m term (sinc = 1)
        int n1 = 2*m - 127, tt = 2*(o - m);
        double ang = chc*(double)(n1*n1) + c*(double)(tt*tt);
        double r = ang*inv2pi; r -= floor(r);
        float af = (float)(r*2.0*PI_D);
        float sn, cs; __sincosf(af, &sn, &cs);
        sr = cs; si = sn;
    }
    for (int j = 0; j < 127; ++j) {
        int q  = 2*j + 1;
        int n1 = q - 127, tt = 2*o - q, d = q - 2*m;
        double ang = chc*(double)(n1*n1) + c*(double)(tt*tt);
        double r = ang*inv2pi; r -= floor(r);
        float af = (float)(r*2.0*PI_D);
        float s = (((d-1)>>1) & 1) ? -2.0f : 2.0f;
        s /= (3.14159265358979f*(float)d);
        float sn, cs; __sincosf(af, &sn, &cs);
        sr += s*cs; si += s*sn;
    }
    int n2 = 2*o - 127;
    double ph = chc*(double)(n2*n2) - PI_D/8.0;
    double r = ph*inv2pi; r -= floor(r);
    float pf = (float)(r*2.0*PI_D);
    float scale = (float)sqrt(c/PI_D);
    float sn, cs; __sincosf(pf, &sn, &cs);
    float cr = cs*scale, ci = sn*scale;
    g_Mf[tid] = make_float2(sr*cr - si*ci, sr*ci + si*cr);
}

__global__ void k_build_Mbf() {
    __shared__ float2 W[128];
    int t = threadIdx.x;
    if (t < 128) {
        float ang = TWO_PI_F*(float)t/128.0f;
        float sn, cs; sincosf(ang, &sn, &cs);
        float invs = 0.08838834764831845f;
        W[t] = make_float2(cs*invs, sn*invs);
    }
    __syncthreads();
    int tid = blockIdx.x*blockDim.x + t;
    if (tid >= 128*128) return;
    int o = tid >> 7, m = tid & 127;
    float sr = 0.f, si = 0.f;
    for (int r = 0; r < 128; ++r) {
        float2 a = g_Mf[(o<<7) + r];
        int k = ((r+64)*(m+64)) & 127;
        float2 w = W[k];
        sr += a.x*w.x - a.y*w.y;
        si += a.x*w.y + a.y*w.x;
    }
    g_Mb[tid] = make_float2(sr, si);
}

__global__ void k_build_Ff() {
    int tid = blockIdx.x*blockDim.x + threadIdx.x;
    if (tid >= 128*128) return;
    int k = tid >> 7, n = tid & 127;
    int p = (k*n) & 127;
    float ang = TWO_PI_F*(float)p/128.0f;
    float sn, cs; sincosf(ang, &sn, &cs);
    g_F[tid]  = make_float2(cs, -sn);
    g_IF[tid] = make_float2(cs*0.0078125f, sn*0.0078125f);
}

// ---------------- transform GEMMs: 64x64 tile, 4x4 micro --------------------
// Loader modes (T-side of rmul):
// 0: complex natural   1: real from x1 slice   2: mag/pha full plane (fused combine)
// 3: mag/pha packed65 + Hermitian extension (fused combine65+extend)
template<int LM>
__device__ inline void load_T8(float2* tr, const float* mp, const float* pp,
                               const float2* Tc, const float* Trl,
                               int hh, int w8) {
    if (LM == 0) {
        const float4* src = (const float4*)(Tc + (hh<<7) + w8);
#pragma unroll
        for (int i = 0; i < 4; ++i) {
            float4 v = src[i];
            tr[2*i]   = make_float2(v.x, v.y);
            tr[2*i+1] = make_float2(v.z, v.w);
        }
    } else if (LM == 1) {
        const float4* src = (const float4*)(Trl + (hh<<7) + w8);
#pragma unroll
        for (int i = 0; i < 2; ++i) {
            float4 v = src[i];
            tr[4*i]   = make_float2(v.x, 0.f);
            tr[4*i+1] = make_float2(v.y, 0.f);
            tr[4*i+2] = make_float2(v.z, 0.f);
            tr[4*i+3] = make_float2(v.w, 0.f);
        }
    } else if (LM == 2) {
#pragma unroll
        for (int i = 0; i < 8; ++i) {
            int idx = (hh<<7) + w8 + i;
            float m = mp[idx], ph = pp[idx];
            float sn, cs; __sincosf(ph, &sn, &cs);
            tr[i] = make_float2(m*cs, m*sn);
        }
    } else {
#pragma unroll
        for (int i = 0; i < 8; ++i) {
            int w = w8 + i;
            int h2 = hh, w2 = w; float sg = 1.f;
            if (w >= 65) { h2 = (128 - hh) & 127; w2 = 128 - w; sg = -1.f; }
            int idx = h2*65 + w2;
            float m = mp[idx], ph = pp[idx];
            float sn, cs; __sincosf(ph, &sn, &cs);
            tr[i] = make_float2(m*cs, sg*m*sn);
        }
    }
}

// out[p,h,j] = sum_w T[p,h,w] * A[j,w]
template<int LM>
__global__ void k_rmul64(const float2* __restrict__ A, const float2* __restrict__ Tc,
                         const float* __restrict__ Trl, const float* __restrict__ mp_,
                         const float* __restrict__ pp_, float2* __restrict__ out,
                         int Ctot, int Csub, int cstart) {
    __shared__ float2 Ts[64][34];
    __shared__ float2 As[64][34];
    int p  = blockIdx.z;
    int h0 = blockIdx.y << 6, j0 = blockIdx.x << 6;
    int t  = threadIdx.x;
    int tx = t & 15, ty = t >> 4;
    int lr = t >> 2, l8 = (t & 3) * 8;
    const float2* Tcp = nullptr; const float* Trp = nullptr;
    const float* mp = nullptr; const float* pp = nullptr;
    if (LM == 0) Tcp = Tc + ((long)p << 14);
    if (LM == 1) { int n = p / Csub, c = p - n*Csub; Trp = Trl + ((long)(n*Ctot + cstart + c) << 14); }
    if (LM == 2) { mp = mp_ + ((long)p << 14); pp = pp_ + ((long)p << 14); }
    if (LM == 3) { mp = mp_ + (long)p*8320;   pp = pp_ + (long)p*8320; }
    float2 treg[8], areg[8];
    load_T8<LM>(treg, mp, pp, Tcp, Trp, h0 + lr, l8);
    {
        const float4* s = (const float4*)(A + ((j0 + lr) << 7) + l8);
#pragma unroll
        for (int i = 0; i < 4; ++i) {
            float4 v = s[i];
            areg[2*i]   = make_float2(v.x, v.y);
            areg[2*i+1] = make_float2(v.z, v.w);
        }
    }
    float2 acc[4][4] = {};
    for (int kc = 0; kc < 128; kc += 32) {
        __syncthreads();
        {
            float4* dT = (float4*)&Ts[lr][l8];
            float4* dA = (float4*)&As[lr][l8];
#pragma unroll
            for (int i = 0; i < 4; ++i) {
                dT[i] = make_float4(treg[2*i].x, treg[2*i].y, treg[2*i+1].x, treg[2*i+1].y);
                dA[i] = make_float4(areg[2*i].x, areg[2*i].y, areg[2*i+1].x, areg[2*i+1].y);
            }
        }
        __syncthreads();
        if (kc < 96) {
            load_T8<LM>(treg, mp, pp, Tcp, Trp, h0 + lr, kc + 32 + l8);
            const float4* s = (const float4*)(A + ((j0 + lr) << 7) + kc + 32 + l8);
#pragma unroll
            for (int i = 0; i < 4; ++i) {
                float4 v = s[i];
                areg[2*i]   = make_float2(v.x, v.y);
                areg[2*i+1] = make_float2(v.z, v.w);
            }
        }
#pragma unroll
        for (int kk = 0; kk < 32; ++kk) {
            float2 av[4], bv[4];
#pragma unroll
            for (int i = 0; i < 4; ++i) av[i] = Ts[4*ty + i][kk];
#pragma unroll
            for (int j = 0; j < 4; ++j) bv[j] = As[tx + 16*j][kk];
#pragma unroll
            for (int i = 0; i < 4; ++i)
#pragma unroll
                for (int j = 0; j < 4; ++j) {
                    acc[i][j].x += av[i].x*bv[j].x - av[i].y*bv[j].y;
                    acc[i][j].y += av[i].x*bv[j].y + av[i].y*bv[j].x;
                }
        }
    }
    long base = ((long)p << 14);
#pragma unroll
    for (int i = 0; i < 4; ++i)
#pragma unroll
        for (int j = 0; j < 4; ++j)
            out[base + ((h0 + 4*ty + i) << 7) + j0 + tx + 16*j] = acc[i][j];
}

// out[p,j,w] = sum_h A[j,h] * T[p,h,w]; fused epilogues:
// EPI 1: mag/pha full -> o1,o2   2: abs->cat(o1)+coff   3: real->cat(o1)+coff
// EPI 4: mag/pha packed w<65 -> o1,o2
template<int EPI>
__global__ void k_lmul64(const float2* __restrict__ A, const float2* __restrict__ in,
                         float* __restrict__ o1, float* __restrict__ o2, int coff) {
    __shared__ float2 As[64][34];
    __shared__ float2 Ts[32][66];
    int p  = blockIdx.z;
    int j0 = blockIdx.y << 6, w0 = blockIdx.x << 6;
    int t  = threadIdx.x;
    int tx = t & 15, ty = t >> 4;
    int alr = t >> 2, al8 = (t & 3) * 8;
    int tlr = t >> 3, tl8 = (t & 7) * 8;
    const float2* T = in + ((long)p << 14);
    float2 areg[8], treg[8];
    {
        const float4* sA = (const float4*)(A + ((j0 + alr) << 7) + al8);
        const float4* sT = (const float4*)(T + (tlr << 7) + w0 + tl8);
#pragma unroll
        for (int i = 0; i < 4; ++i) {
            float4 va = sA[i], vt = sT[i];
            areg[2*i] = make_float2(va.x, va.y); areg[2*i+1] = make_float2(va.z, va.w);
            treg[2*i] = make_float2(vt.x, vt.y); treg[2*i+1] = make_float2(vt.z, vt.w);
        }
    }
    float2 acc[4][4] = {};
    for (int kc = 0; kc < 128; kc += 32) {
        __syncthreads();
        {
            float4* dA = (float4*)&As[alr][al8];
            float4* dT = (float4*)&Ts[tlr][tl8];
#pragma unroll
            for (int i = 0; i < 4; ++i) {
                dA[i] = make_float4(areg[2*i].x, areg[2*i].y, areg[2*i+1].x, areg[2*i+1].y);
                dT[i] = make_float4(treg[2*i].x, treg[2*i].y, treg[2*i+1].x, treg[2*i+1].y);
            }
        }
        __syncthreads();
        if (kc < 96) {
            const float4* sA = (const float4*)(A + ((j0 + alr) << 7) + kc + 32 + al8);
            const float4* sT = (const float4*)(T + ((kc + 32 + tlr) << 7) + w0 + tl8);
#pragma unroll
            for (int i = 0; i < 4; ++i) {
                float4 va = sA[i], vt = sT[i];
                areg[2*i] = make_float2(va.x, va.y); areg[2*i+1] = make_float2(va.z, va.w);
                treg[2*i] = make_float2(vt.x, vt.y); treg[2*i+1] = make_float2(vt.z, vt.w);
            }
        }
#pragma unroll
        for (int kk = 0; kk < 32; ++kk) {
            float2 av[4], bv[4];
#pragma unroll
            for (int i = 0; i < 4; ++i) av[i] = As[4*ty + i][kk];
#pragma unroll
            for (int j = 0; j < 4; ++j) bv[j] = Ts[kk][tx + 16*j];
#pragma unroll
            for (int i = 0; i < 4; ++i)
#pragma unroll
                for (int j = 0; j < 4; ++j) {
                    acc[i][j].x += av[i].x*bv[j].x - av[i].y*bv[j].y;
                    acc[i][j].y += av[i].x*bv[j].y + av[i].y*bv[j].x;
                }
        }
    }
#pragma unroll
    for (int i = 0; i < 4; ++i) {
#pragma unroll
        for (int j = 0; j < 4; ++j) {
            int jj = j0 + 4*ty + i;
            int ww = w0 + tx + 16*j;
            float2 v = acc[i][j];
            if (EPI == 1) {
                long idx = ((long)p << 14) + (jj << 7) + ww;
                o1[idx] = sqrtf(v.x*v.x + v.y*v.y);
                o2[idx] = atan2f(v.y, v.x);
            } else if (EPI == 2) {
                int n = p >> 4, c = p & 15;
                o1[((long)(n*48 + coff + c) << 14) + (jj << 7) + ww] = sqrtf(v.x*v.x + v.y*v.y);
            } else if (EPI == 3) {
                int n = p >> 4, c = p & 15;
                o1[((long)(n*48 + coff + c) << 14) + (jj << 7) + ww] = v.x;
            } else if (EPI == 4) {
                if (ww < 65) {
                    long idx = (long)p*8320 + jj*65 + ww;
                    o1[idx] = sqrtf(v.x*v.x + v.y*v.y);
                    o2[idx] = atan2f(v.y, v.x);
                }
            }
        }
    }
}

// ---------------- 1x1 conv: per-wave outputs, prefetch dbuf -----------------
template<int CIN, int COUT, int VEC>
__global__ void k_conv(const float* __restrict__ in, const float* __restrict__ wgt,
                       const float* __restrict__ bias, float* __restrict__ out,
                       int Ctin, int cstart, int Ctout, int costart) {
    const int S = 16384;
    const int STILE = 64*VEC;
    const int OW = COUT/4;
    __shared__ float xs[8][STILE];
    int n  = blockIdx.y;
    int s0 = blockIdx.x * STILE;
    int t  = threadIdx.x, lane = t & 63;
    int wid = __builtin_amdgcn_readfirstlane(t >> 6);
    const float* wb  = wgt + wid*OW*CIN;
    const float* inb = in + ((long)(n*Ctin + cstart))*S + s0;
    float acc[OW][VEC] = {};
    float4 r0, r1;
    // prefetch chunk 0
    if (VEC == 4) {
        r0 = *(const float4*)(inb + (long)(t>>6)*S + (t&63)*4);
        r1 = *(const float4*)(inb + (long)((t>>6)+4)*S + (t&63)*4);
    } else {
        r0 = *(const float4*)(inb + (long)(t>>5)*S + (t&31)*4);
    }
    for (int c0 = 0; c0 < CIN; c0 += 8) {
        __syncthreads();
        if (VEC == 4) {
            *(float4*)&xs[t>>6][(t&63)*4] = r0;
            *(float4*)&xs[(t>>6)+4][(t&63)*4] = r1;
        } else {
            *(float4*)&xs[t>>5][(t&31)*4] = r0;
        }
        __syncthreads();
        if (c0 + 8 < CIN) {
            if (VEC == 4) {
                r0 = *(const float4*)(inb + (long)(c0+8 + (t>>6))*S + (t&63)*4);
                r1 = *(const float4*)(inb + (long)(c0+12 + (t>>6))*S + (t&63)*4);
            } else {
                r0 = *(const float4*)(inb + (long)(c0+8 + (t>>5))*S + (t&31)*4);
            }
        }
#pragma unroll
        for (int cc = 0; cc < 8; ++cc) {
            float xv[VEC];
#pragma unroll
            for (int v = 0; v < VEC; ++v) xv[v] = xs[cc][lane*VEC + v];
#pragma unroll
            for (int j = 0; j < OW; ++j) {
                float wv = wb[j*CIN + c0 + cc];
#pragma unroll
                for (int v = 0; v < VEC; ++v) acc[j][v] += wv*xv[v];
            }
        }
    }
#pragma unroll
    for (int j = 0; j < OW; ++j) {
        int o = wid*OW + j;
        float bvv = bias ? bias[o] : 0.f;
        float* op = out + ((long)(n*Ctout + costart + o))*S + s0 + lane*VEC;
        if (VEC == 4) {
            *(float4*)op = make_float4(acc[j][0]+bvv, acc[j][1]+bvv, acc[j][2]+bvv, acc[j][3]+bvv);
        } else {
            *(float2*)op = make_float2(acc[j][0]+bvv, acc[j][1]+bvv);
        }
    }
}

// ---------------- old conv (kept for packed S=8320 arrays) ------------------
template<int CIN, int COUT>
__global__ void k_conv1x1t(const float* __restrict__ in, const float* __restrict__ w,
                           const float* __restrict__ b, float* __restrict__ out,
                           int S, int Ctot_in, int Ctot_out) {
    __shared__ float xs[4][64];
    __shared__ float ws[4][COUT];
    int n  = blockIdx.y;
    int s0 = blockIdx.x * 64;
    int t  = threadIdx.x;
    int sl = t & 63;
    int og = t >> 6;
    const int NO = COUT/4;
    float acc[NO];
#pragma unroll
    for (int j = 0; j < NO; ++j) acc[j] = 0.f;
    const float* inb = in + (long)n*Ctot_in*S + s0;
    for (int c0 = 0; c0 < CIN; c0 += 4) {
        xs[og][sl] = inb[(long)(c0+og)*S + sl];
        for (int i = t; i < 4*COUT; i += 256) {
            int cc = i / COUT, oo = i - cc*COUT;
            ws[cc][oo] = w[oo*CIN + c0 + cc];
        }
        __syncthreads();
#pragma unroll
        for (int cc = 0; cc < 4; ++cc) {
            float xv = xs[cc][sl];
#pragma unroll
            for (int j = 0; j < NO; ++j)
                acc[j] += ws[cc][og + 4*j] * xv;
        }
        __syncthreads();
    }
#pragma unroll
    for (int j = 0; j < NO; ++j) {
        int o = og + 4*j;
        float v = acc[j] + (b ? b[o] : 0.f);
        out[((long)n*Ctot_out + o)*S + s0 + sl] = v;
    }
}

// ---------------- maskconv --------------------------------------------------
__global__ void k_maskconv(const float* __restrict__ mag, const float* __restrict__ ws3,
                           const float* __restrict__ bs, const float* __restrict__ wf,
                           const float* __restrict__ bf, float* __restrict__ out) {
    int tid = blockIdx.x*blockDim.x + threadIdx.x;
    if (tid >= 4*16*16384) return;
    int w = tid & 127, h = (tid >> 7) & 127, o = (tid >> 14) & 15, n = tid >> 18;
    const float* mp = mag + (long)n*16*16384;
    bool in1 = (h >= 19 && h < 109 && w >= 19 && w < 109);
    float acc;
    if (in1) {
        acc = bs[o];
        for (int c = 0; c < 16; ++c) {
            const float* xp = mp + c*16384;
            const float* wp = ws3 + (o*16 + c)*9;
#pragma unroll
            for (int dh = -1; dh <= 1; ++dh)
#pragma unroll
                for (int dw = -1; dw <= 1; ++dw) {
                    int hh = h + dh, ww = w + dw;
                    if (hh >= 19 && hh < 109 && ww >= 19 && ww < 109)
                        acc += wp[(dh+1)*3 + (dw+1)] * xp[hh*128 + ww];
                }
        }
    } else {
        acc = bf[o];
        for (int c = 0; c < 16; ++c)
            acc += wf[o*16 + c] * mp[c*16384 + h*128 + w];
    }
    out[tid] = acc;
}

// ---------------- launch ----------------------------------------------------
extern "C" void kernel_launch(void* const* d_in, const int* in_sizes, int n_in,
                              void* d_out, int out_size, void* d_ws, size_t ws_size,
                              hipStream_t stream) {
    (void)in_sizes; (void)n_in; (void)out_size; (void)d_ws; (void)ws_size;
    const float* x        = (const float*)d_in[0];
    const float* conv1_w  = (const float*)d_in[1];
    const float* mag_s_w  = (const float*)d_in[2];
    const float* mag_s_b  = (const float*)d_in[3];
    const float* mag_f_w  = (const float*)d_in[4];
    const float* mag_f_b  = (const float*)d_in[5];
    const float* mag_w_   = (const float*)d_in[6];
    const float* mag_b_   = (const float*)d_in[7];
    const float* pha_w_   = (const float*)d_in[8];
    const float* pha_b_   = (const float*)d_in[9];
    const float* conv_0_w = (const float*)d_in[10];
    const float* conv_0_b = (const float*)d_in[11];
    const float* conv_1_w = (const float*)d_in[12];
    const float* conv_1_b = (const float*)d_in[13];
    const float* conv2_w  = (const float*)d_in[14];
    float* outp = (float*)d_out;

    float2 *Mf, *Mb, *Fm, *IFm, *bufA;
    float *x1, *mag, *pha, *t1, *t2, *cat;
    hipGetSymbolAddress((void**)&Mf,   HIP_SYMBOL(g_Mf));
    hipGetSymbolAddress((void**)&Mb,   HIP_SYMBOL(g_Mb));
    hipGetSymbolAddress((void**)&Fm,   HIP_SYMBOL(g_F));
    hipGetSymbolAddress((void**)&IFm,  HIP_SYMBOL(g_IF));
    hipGetSymbolAddress((void**)&bufA, HIP_SYMBOL(g_bufA));
    hipGetSymbolAddress((void**)&x1,   HIP_SYMBOL(g_x1));
    hipGetSymbolAddress((void**)&mag,  HIP_SYMBOL(g_mag));
    hipGetSymbolAddress((void**)&pha,  HIP_SYMBOL(g_pha));
    hipGetSymbolAddress((void**)&t1,   HIP_SYMBOL(g_t1));
    hipGetSymbolAddress((void**)&t2,   HIP_SYMBOL(g_t2));
    hipGetSymbolAddress((void**)&cat,  HIP_SYMBOL(g_cat));

    dim3 gt(2,2,64), bt(256,1,1);

    // matrices
    k_build_M05f<<<64, 256, 0, stream>>>();
    k_build_Mbf <<<64, 256, 0, stream>>>();
    k_build_Ff  <<<64, 256, 0, stream>>>();

    // x1 = 1x1 conv (192 -> 48)
    k_conv<192,48,4><<<dim3(64,4), 256, 0, stream>>>(x, conv1_w, nullptr, x1, 192, 0, 48, 0);

    // FRFT forward on x_05 (ch 16..31): Fre = Mf X Mf^T; fused mag/pha
    k_rmul64<1><<<gt, bt, 0, stream>>>(Mf, nullptr, x1, nullptr, nullptr, bufA, 48, 16, 16);
    k_lmul64<1><<<gt, bt, 0, stream>>>(Mf, bufA, mag, pha, 0);

    // masked convs + channel mixes
    k_maskconv<<<4096, 256, 0, stream>>>(mag, mag_s_w, mag_s_b, mag_f_w, mag_f_b, t1);
    k_conv<16,16,4><<<dim3(64,4), 256, 0, stream>>>(t1,  mag_w_, mag_b_, t2, 16, 0, 16, 0);
    k_conv<16,16,4><<<dim3(64,4), 256, 0, stream>>>(pha, pha_w_, pha_b_, t1, 16, 0, 16, 0);

    // FRFT backward (combine fused into loader): |Mb Y Mb^T| -> cat ch 16..31
    k_rmul64<2><<<gt, bt, 0, stream>>>(Mb, nullptr, nullptr, t2, t1, bufA, 0, 0, 0);
    k_lmul64<2><<<gt, bt, 0, stream>>>(Mb, bufA, cat, nullptr, 16);

    // FFT branch on x_1 (ch 32..47): G = F X F^T; fused packed mag/pha
    k_rmul64<1><<<gt, bt, 0, stream>>>(Fm, nullptr, x1, nullptr, nullptr, bufA, 48, 16, 32);
    k_lmul64<4><<<gt, bt, 0, stream>>>(Fm, bufA, mag, pha, 0);
    k_conv1x1t<16,16><<<dim3(130,4), 256, 0, stream>>>(mag, conv_1_w, conv_1_b, t1, 8320, 16, 16);
    k_conv1x1t<16,16><<<dim3(130,4), 256, 0, stream>>>(pha, conv_1_w, conv_1_b, t2, 8320, 16, 16);
    // inverse rfft2 (combine65 + Hermitian extension fused into loader)
    k_rmul64<3><<<gt, bt, 0, stream>>>(IFm, nullptr, nullptr, t1, t2, bufA, 0, 0, 0);
    k_lmul64<3><<<gt, bt, 0, stream>>>(IFm, bufA, cat, nullptr, 32);

    // x_0o -> cat ch 0..15
    k_conv<16,16,4><<<dim3(64,4), 256, 0, stream>>>(x1, conv_0_w, conv_0_b, cat, 48, 0, 48, 0);

    // final 1x1 conv (48 -> 192)
    k_conv<48,192,2><<<dim3(128,4), 256, 0, stream>>>(cat, conv2_w, nullptr, outp, 48, 0, 192, 0);
}

// Round 4
// 587.347 us; speedup vs baseline: 3.4273x; 3.4273x over previous
//
#include <hip/hip_runtime.h>
#include <math.h>

#define PI_D 3.14159265358979323846
#define TWO_PI_F 6.2831853071795864f

// ---------------- persistent device buffers ---------------------------------
__device__ __align__(16) float2  g_Mf [128*128];
__device__ __align__(16) float2  g_Mb [128*128];
__device__ __align__(16) float2  g_F  [128*128];
__device__ __align__(16) float2  g_IF [128*128];
__device__ __align__(16) float   g_x1 [4*48*16384];
__device__ __align__(16) float2  g_bufA[64*16384];
__device__ __align__(16) float   g_mag[64*16384];
__device__ __align__(16) float   g_pha[64*16384];
__device__ __align__(16) float   g_t1 [64*16384];
__device__ __align__(16) float   g_t2 [64*16384];
__device__ __align__(16) float   g_cat[4*48*16384];

// ---------------- matrix builders -------------------------------------------
__global__ void k_build_M05f() {
    int tid = blockIdx.x*blockDim.x + threadIdx.x;
    if (tid >= 128*128) return;
    int o = tid >> 7, m = tid & 127;
    const double chc = -PI_D/128.0 * tan(PI_D/8.0) * 0.25;
    const double c   =  PI_D/(512.0*sin(PI_D/4.0));
    const double inv2pi = 1.0/(2.0*PI_D);
    float sr, si;
    {   // q = 2m term (sinc = 1)
        int n1 = 2*m - 127, tt = 2*(o - m);
        double ang = chc*(double)(n1*n1) + c*(double)(tt*tt);
        double r = ang*inv2pi; r -= floor(r);
        float af = (float)(r*2.0*PI_D);
        float sn, cs; __sincosf(af, &sn, &cs);
        sr = cs; si = sn;
    }
    for (int j = 0; j < 127; ++j) {
        int q  = 2*j + 1;
        int n1 = q - 127, tt = 2*o - q, d = q - 2*m;
        double ang = chc*(double)(n1*n1) + c*(double)(tt*tt);
        double r = ang*inv2pi; r -= floor(r);
        float af = (float)(r*2.0*PI_D);
        float s = (((d-1)>>1) & 1) ? -2.0f : 2.0f;
        s /= (3.14159265358979f*(float)d);
        float sn, cs; __sincosf(af, &sn, &cs);
        sr += s*cs; si += s*sn;
    }
    int n2 = 2*o - 127;
    double ph = chc*(double)(n2*n2) - PI_D/8.0;
    double r = ph*inv2pi; r -= floor(r);
    float pf = (float)(r*2.0*PI_D);
    float scale = (float)sqrt(c/PI_D);
    float sn, cs; __sincosf(pf, &sn, &cs);
    float cr = cs*scale, ci = sn*scale;
    g_Mf[tid] = make_float2(sr*cr - si*ci, sr*ci + si*cr);
}

__global__ void k_build_Mbf() {
    __shared__ float2 W[128];
    int t = threadIdx.x;
    if (t < 128) {
        float ang = TWO_PI_F*(float)t/128.0f;
        float sn, cs; sincosf(ang, &sn, &cs);
        float invs = 0.08838834764831845f;
        W[t] = make_float2(cs*invs, sn*invs);
    }
    __syncthreads();
    int tid = blockIdx.x*blockDim.x + t;
    if (tid >= 128*128) return;
    int o = tid >> 7, m = tid & 127;
    float sr = 0.f, si = 0.f;
    for (int r = 0; r < 128; ++r) {
        float2 a = g_Mf[(o<<7) + r];
        int k = ((r+64)*(m+64)) & 127;
        float2 w = W[k];
        sr += a.x*w.x - a.y*w.y;
        si += a.x*w.y + a.y*w.x;
    }
    g_Mb[tid] = make_float2(sr, si);
}

__global__ void k_build_Ff() {
    int tid = blockIdx.x*blockDim.x + threadIdx.x;
    if (tid >= 128*128) return;
    int k = tid >> 7, n = tid & 127;
    int p = (k*n) & 127;
    float ang = TWO_PI_F*(float)p/128.0f;
    float sn, cs; sincosf(ang, &sn, &cs);
    g_F[tid]  = make_float2(cs, -sn);
    g_IF[tid] = make_float2(cs*0.0078125f, sn*0.0078125f);
}

// ---------------- transform GEMMs: 64x64 tile, 4x4 micro --------------------
// Loader modes (T-side of rmul):
// 0: complex natural  1: real from x1 slice  2: mag/pha full plane (fused combine)
// 3: mag/pha packed65 + Hermitian extension (fused combine65+extend)
template<int LM>
__device__ inline void load_T8(float2* tr, const float* mp, const float* pp,
                               const float2* Tc, const float* Trl,
                               int hh, int w8) {
    if (LM == 0) {
        const float4* src = (const float4*)(Tc + (hh<<7) + w8);
#pragma unroll
        for (int i = 0; i < 4; ++i) {
            float4 v = src[i];
            tr[2*i]   = make_float2(v.x, v.y);
            tr[2*i+1] = make_float2(v.z, v.w);
        }
    } else if (LM == 1) {
        const float4* src = (const float4*)(Trl + (hh<<7) + w8);
#pragma unroll
        for (int i = 0; i < 2; ++i) {
            float4 v = src[i];
            tr[4*i]   = make_float2(v.x, 0.f);
            tr[4*i+1] = make_float2(v.y, 0.f);
            tr[4*i+2] = make_float2(v.z, 0.f);
            tr[4*i+3] = make_float2(v.w, 0.f);
        }
    } else if (LM == 2) {
#pragma unroll
        for (int i = 0; i < 8; ++i) {
            int idx = (hh<<7) + w8 + i;
            float m = mp[idx], ph = pp[idx];
            float sn, cs; __sincosf(ph, &sn, &cs);
            tr[i] = make_float2(m*cs, m*sn);
        }
    } else {
#pragma unroll
        for (int i = 0; i < 8; ++i) {
            int w = w8 + i;
            int h2 = hh, w2 = w; float sg = 1.f;
            if (w >= 65) { h2 = (128 - hh) & 127; w2 = 128 - w; sg = -1.f; }
            int idx = h2*65 + w2;
            float m = mp[idx], ph = pp[idx];
            float sn, cs; __sincosf(ph, &sn, &cs);
            tr[i] = make_float2(m*cs, sg*m*sn);
        }
    }
}

// out[p,h,j] = sum_w T[p,h,w] * A[j,w]
template<int LM>
__global__ __launch_bounds__(256, 1)
void k_rmul64(const float2* __restrict__ A, const float2* __restrict__ Tc,
              const float* __restrict__ Trl, const float* __restrict__ mp_,
              const float* __restrict__ pp_, float2* __restrict__ out,
              int Ctot, int Csub, int cstart) {
    __shared__ float2 Ts[64][34];   // [h][k]
    __shared__ float2 As[64][34];   // [j][k]
    int p  = blockIdx.z;
    int h0 = blockIdx.y << 6, j0 = blockIdx.x << 6;
    int t  = threadIdx.x;
    int tx = t & 15, ty = t >> 4;
    int lr = t >> 2, l8 = (t & 3) * 8;
    const float2* Tcp = nullptr; const float* Trp = nullptr;
    const float* mp = nullptr; const float* pp = nullptr;
    if (LM == 0) Tcp = Tc + ((long)p << 14);
    if (LM == 1) { int n = p / Csub, c = p - n*Csub; Trp = Trl + ((long)(n*Ctot + cstart + c) << 14); }
    if (LM == 2) { mp = mp_ + ((long)p << 14); pp = pp_ + ((long)p << 14); }
    if (LM == 3) { mp = mp_ + (long)p*8320;   pp = pp_ + (long)p*8320; }
    float2 acc[4][4] = {};
    for (int kc = 0; kc < 128; kc += 32) {
        __syncthreads();
        {
            float2 treg[8];
            load_T8<LM>(treg, mp, pp, Tcp, Trp, h0 + lr, kc + l8);
            float4* dT = (float4*)&Ts[lr][l8];
#pragma unroll
            for (int i = 0; i < 4; ++i)
                dT[i] = make_float4(treg[2*i].x, treg[2*i].y, treg[2*i+1].x, treg[2*i+1].y);
            const float4* sA = (const float4*)(A + ((j0 + lr) << 7) + kc + l8);
            float4* dA = (float4*)&As[lr][l8];
#pragma unroll
            for (int i = 0; i < 4; ++i)
                dA[i] = sA[i];
        }
        __syncthreads();
#pragma unroll
        for (int kk = 0; kk < 32; ++kk) {
            float2 av[4], bv[4];
#pragma unroll
            for (int i = 0; i < 4; ++i) av[i] = Ts[4*ty + i][kk];
#pragma unroll
            for (int j = 0; j < 4; ++j) bv[j] = As[tx + 16*j][kk];
#pragma unroll
            for (int i = 0; i < 4; ++i)
#pragma unroll
                for (int j = 0; j < 4; ++j) {
                    acc[i][j].x += av[i].x*bv[j].x - av[i].y*bv[j].y;
                    acc[i][j].y += av[i].x*bv[j].y + av[i].y*bv[j].x;
                }
        }
    }
    long base = ((long)p << 14);
#pragma unroll
    for (int i = 0; i < 4; ++i)
#pragma unroll
        for (int j = 0; j < 4; ++j)
            out[base + ((h0 + 4*ty + i) << 7) + j0 + tx + 16*j] = acc[i][j];
}

// out[p,j,w] = sum_h A[j,h] * T[p,h,w]; fused epilogues:
// EPI 1: mag/pha full -> o1,o2   2: abs->cat(o1)+coff   3: real->cat(o1)+coff
// EPI 4: mag/pha packed w<65 -> o1,o2
template<int EPI>
__global__ __launch_bounds__(256, 1)
void k_lmul64(const float2* __restrict__ A, const float2* __restrict__ in,
              float* __restrict__ o1, float* __restrict__ o2, int coff) {
    __shared__ float2 As[64][34];   // [j][h]
    __shared__ float2 Ts[32][66];   // [h][w]
    int p  = blockIdx.z;
    int j0 = blockIdx.y << 6, w0 = blockIdx.x << 6;
    int t  = threadIdx.x;
    int tx = t & 15, ty = t >> 4;
    int alr = t >> 2, al8 = (t & 3) * 8;
    int tlr = t >> 3, tl8 = (t & 7) * 8;
    const float2* T = in + ((long)p << 14);
    float2 acc[4][4] = {};
    for (int kc = 0; kc < 128; kc += 32) {
        __syncthreads();
        {
            const float4* sA = (const float4*)(A + ((j0 + alr) << 7) + kc + al8);
            float4* dA = (float4*)&As[alr][al8];
#pragma unroll
            for (int i = 0; i < 4; ++i) dA[i] = sA[i];
            const float4* sT = (const float4*)(T + ((kc + tlr) << 7) + w0 + tl8);
            float4* dT = (float4*)&Ts[tlr][tl8];
#pragma unroll
            for (int i = 0; i < 4; ++i) dT[i] = sT[i];
        }
        __syncthreads();
#pragma unroll
        for (int kk = 0; kk < 32; ++kk) {
            float2 av[4], bv[4];
#pragma unroll
            for (int i = 0; i < 4; ++i) av[i] = As[4*ty + i][kk];
#pragma unroll
            for (int j = 0; j < 4; ++j) bv[j] = Ts[kk][tx + 16*j];
#pragma unroll
            for (int i = 0; i < 4; ++i)
#pragma unroll
                for (int j = 0; j < 4; ++j) {
                    acc[i][j].x += av[i].x*bv[j].x - av[i].y*bv[j].y;
                    acc[i][j].y += av[i].x*bv[j].y + av[i].y*bv[j].x;
                }
        }
    }
#pragma unroll
    for (int i = 0; i < 4; ++i) {
#pragma unroll
        for (int j = 0; j < 4; ++j) {
            int jj = j0 + 4*ty + i;
            int ww = w0 + tx + 16*j;
            float2 v = acc[i][j];
            if (EPI == 1) {
                long idx = ((long)p << 14) + (jj << 7) + ww;
                o1[idx] = sqrtf(v.x*v.x + v.y*v.y);
                o2[idx] = atan2f(v.y, v.x);
            } else if (EPI == 2) {
                int n = p >> 4, c = p & 15;
                o1[((long)(n*48 + coff + c) << 14) + (jj << 7) + ww] = sqrtf(v.x*v.x + v.y*v.y);
            } else if (EPI == 3) {
                int n = p >> 4, c = p & 15;
                o1[((long)(n*48 + coff + c) << 14) + (jj << 7) + ww] = v.x;
            } else if (EPI == 4) {
                if (ww < 65) {
                    long idx = (long)p*8320 + jj*65 + ww;
                    o1[idx] = sqrtf(v.x*v.x + v.y*v.y);
                    o2[idx] = atan2f(v.y, v.x);
                }
            }
        }
    }
}

// ---------------- 1x1 conv: per-wave outputs, prefetch dbuf -----------------
template<int CIN, int COUT, int VEC>
__global__ __launch_bounds__(256, 1)
void k_conv(const float* __restrict__ in, const float* __restrict__ wgt,
            const float* __restrict__ bias, float* __restrict__ out,
            int Ctin, int cstart, int Ctout, int costart) {
    const int S = 16384;
    const int STILE = 64*VEC;
    const int OW = COUT/4;
    __shared__ float xs[8][STILE];
    int n  = blockIdx.y;
    int s0 = blockIdx.x * STILE;
    int t  = threadIdx.x, lane = t & 63;
    int wid = __builtin_amdgcn_readfirstlane(t >> 6);
    const float* wb  = wgt + wid*OW*CIN;
    const float* inb = in + ((long)(n*Ctin + cstart))*S + s0;
    float acc[OW][VEC] = {};
    for (int c0 = 0; c0 < CIN; c0 += 8) {
        __syncthreads();
        if (VEC == 4) {
            *(float4*)&xs[t>>6][(t&63)*4]     = *(const float4*)(inb + (long)(c0 + (t>>6))*S + (t&63)*4);
            *(float4*)&xs[(t>>6)+4][(t&63)*4] = *(const float4*)(inb + (long)(c0+4 + (t>>6))*S + (t&63)*4);
        } else {
            *(float4*)&xs[t>>5][(t&31)*4]     = *(const float4*)(inb + (long)(c0 + (t>>5))*S + (t&31)*4);
        }
        __syncthreads();
#pragma unroll
        for (int cc = 0; cc < 8; ++cc) {
            float xv[VEC];
#pragma unroll
            for (int v = 0; v < VEC; ++v) xv[v] = xs[cc][lane*VEC + v];
#pragma unroll
            for (int j = 0; j < OW; ++j) {
                float wv = wb[j*CIN + c0 + cc];
#pragma unroll
                for (int v = 0; v < VEC; ++v) acc[j][v] += wv*xv[v];
            }
        }
    }
#pragma unroll
    for (int j = 0; j < OW; ++j) {
        int o = wid*OW + j;
        float bvv = bias ? bias[o] : 0.f;
        float* op = out + ((long)(n*Ctout + costart + o))*S + s0 + lane*VEC;
        if (VEC == 4) {
            *(float4*)op = make_float4(acc[j][0]+bvv, acc[j][1]+bvv, acc[j][2]+bvv, acc[j][3]+bvv);
        } else {
            *(float2*)op = make_float2(acc[j][0]+bvv, acc[j][1]+bvv);
        }
    }
}

// ---------------- old conv (kept for packed S=8320 arrays) ------------------
template<int CIN, int COUT>
__global__ __launch_bounds__(256, 1)
void k_conv1x1t(const float* __restrict__ in, const float* __restrict__ w,
                const float* __restrict__ b, float* __restrict__ out,
                int S, int Ctot_in, int Ctot_out) {
    __shared__ float xs[4][64];
    __shared__ float ws[4][COUT];
    int n  = blockIdx.y;
    int s0 = blockIdx.x * 64;
    int t  = threadIdx.x;
    int sl = t & 63;
    int og = t >> 6;
    const int NO = COUT/4;
    float acc[NO];
#pragma unroll
    for (int j = 0; j < NO; ++j) acc[j] = 0.f;
    const float* inb = in + (long)n*Ctot_in*S + s0;
    for (int c0 = 0; c0 < CIN; c0 += 4) {
        xs[og][sl] = inb[(long)(c0+og)*S + sl];
        for (int i = t; i < 4*COUT; i += 256) {
            int cc = i / COUT, oo = i - cc*COUT;
            ws[cc][oo] = w[oo*CIN + c0 + cc];
        }
        __syncthreads();
#pragma unroll
        for (int cc = 0; cc < 4; ++cc) {
            float xv = xs[cc][sl];
#pragma unroll
            for (int j = 0; j < NO; ++j)
                acc[j] += ws[cc][og + 4*j] * xv;
        }
        __syncthreads();
    }
#pragma unroll
    for (int j = 0; j < NO; ++j) {
        int o = og + 4*j;
        float v = acc[j] + (b ? b[o] : 0.f);
        out[((long)n*Ctot_out + o)*S + s0 + sl] = v;
    }
}

// ---------------- maskconv --------------------------------------------------
__global__ void k_maskconv(const float* __restrict__ mag, const float* __restrict__ ws3,
                           const float* __restrict__ bs, const float* __restrict__ wf,
                           const float* __restrict__ bf, float* __restrict__ out) {
    int tid = blockIdx.x*blockDim.x + threadIdx.x;
    if (tid >= 4*16*16384) return;
    int w = tid & 127, h = (tid >> 7) & 127, o = (tid >> 14) & 15, n = tid >> 18;
    const float* mp = mag + (long)n*16*16384;
    bool in1 = (h >= 19 && h < 109 && w >= 19 && w < 109);
    float acc;
    if (in1) {
        acc = bs[o];
        for (int c = 0; c < 16; ++c) {
            const float* xp = mp + c*16384;
            const float* wp = ws3 + (o*16 + c)*9;
#pragma unroll
            for (int dh = -1; dh <= 1; ++dh)
#pragma unroll
                for (int dw = -1; dw <= 1; ++dw) {
                    int hh = h + dh, ww = w + dw;
                    if (hh >= 19 && hh < 109 && ww >= 19 && ww < 109)
                        acc += wp[(dh+1)*3 + (dw+1)] * xp[hh*128 + ww];
                }
        }
    } else {
        acc = bf[o];
        for (int c = 0; c < 16; ++c)
            acc += wf[o*16 + c] * mp[c*16384 + h*128 + w];
    }
    out[tid] = acc;
}

// ---------------- launch ----------------------------------------------------
extern "C" void kernel_launch(void* const* d_in, const int* in_sizes, int n_in,
                              void* d_out, int out_size, void* d_ws, size_t ws_size,
                              hipStream_t stream) {
    (void)in_sizes; (void)n_in; (void)out_size; (void)d_ws; (void)ws_size;
    const float* x        = (const float*)d_in[0];
    const float* conv1_w  = (const float*)d_in[1];
    const float* mag_s_w  = (const float*)d_in[2];
    const float* mag_s_b  = (const float*)d_in[3];
    const float* mag_f_w  = (const float*)d_in[4];
    const float* mag_f_b  = (const float*)d_in[5];
    const float* mag_w_   = (const float*)d_in[6];
    const float* mag_b_   = (const float*)d_in[7];
    const float* pha_w_   = (const float*)d_in[8];
    const float* pha_b_   = (const float*)d_in[9];
    const float* conv_0_w = (const float*)d_in[10];
    const float* conv_0_b = (const float*)d_in[11];
    const float* conv_1_w = (const float*)d_in[12];
    const float* conv_1_b = (const float*)d_in[13];
    const float* conv2_w  = (const float*)d_in[14];
    float* outp = (float*)d_out;

    float2 *Mf, *Mb, *Fm, *IFm, *bufA;
    float *x1, *mag, *pha, *t1, *t2, *cat;
    hipGetSymbolAddress((void**)&Mf,   HIP_SYMBOL(g_Mf));
    hipGetSymbolAddress((void**)&Mb,   HIP_SYMBOL(g_Mb));
    hipGetSymbolAddress((void**)&Fm,   HIP_SYMBOL(g_F));
    hipGetSymbolAddress((void**)&IFm,  HIP_SYMBOL(g_IF));
    hipGetSymbolAddress((void**)&bufA, HIP_SYMBOL(g_bufA));
    hipGetSymbolAddress((void**)&x1,   HIP_SYMBOL(g_x1));
    hipGetSymbolAddress((void**)&mag,  HIP_SYMBOL(g_mag));
    hipGetSymbolAddress((void**)&pha,  HIP_SYMBOL(g_pha));
    hipGetSymbolAddress((void**)&t1,   HIP_SYMBOL(g_t1));
    hipGetSymbolAddress((void**)&t2,   HIP_SYMBOL(g_t2));
    hipGetSymbolAddress((void**)&cat,  HIP_SYMBOL(g_cat));

    dim3 gt(2,2,64), bt(256,1,1);

    // matrices
    k_build_M05f<<<64, 256, 0, stream>>>();
    k_build_Mbf <<<64, 256, 0, stream>>>();
    k_build_Ff  <<<64, 256, 0, stream>>>();

    // x1 = 1x1 conv (192 -> 48)
    k_conv<192,48,4><<<dim3(64,4), 256, 0, stream>>>(x, conv1_w, nullptr, x1, 192, 0, 48, 0);

    // FRFT forward on x_05 (ch 16..31): Fre = Mf X Mf^T; fused mag/pha
    k_rmul64<1><<<gt, bt, 0, stream>>>(Mf, nullptr, x1, nullptr, nullptr, bufA, 48, 16, 16);
    k_lmul64<1><<<gt, bt, 0, stream>>>(Mf, bufA, mag, pha, 0);

    // masked convs + channel mixes
    k_maskconv<<<4096, 256, 0, stream>>>(mag, mag_s_w, mag_s_b, mag_f_w, mag_f_b, t1);
    k_conv<16,16,4><<<dim3(64,4), 256, 0, stream>>>(t1,  mag_w_, mag_b_, t2, 16, 0, 16, 0);
    k_conv<16,16,4><<<dim3(64,4), 256, 0, stream>>>(pha, pha_w_, pha_b_, t1, 16, 0, 16, 0);

    // FRFT backward (combine fused into loader): |Mb Y Mb^T| -> cat ch 16..31
    k_rmul64<2><<<gt, bt, 0, stream>>>(Mb, nullptr, nullptr, t2, t1, bufA, 0, 0, 0);
    k_lmul64<2><<<gt, bt, 0, stream>>>(Mb, bufA, cat, nullptr, 16);

    // FFT branch on x_1 (ch 32..47): G = F X F^T; fused packed mag/pha
    k_rmul64<1><<<gt, bt, 0, stream>>>(Fm, nullptr, x1, nullptr, nullptr, bufA, 48, 16, 32);
    k_lmul64<4><<<gt, bt, 0, stream>>>(Fm, bufA, mag, pha, 0);
    k_conv1x1t<16,16><<<dim3(130,4), 256, 0, stream>>>(mag, conv_1_w, conv_1_b, t1, 8320, 16, 16);
    k_conv1x1t<16,16><<<dim3(130,4), 256, 0, stream>>>(pha, conv_1_w, conv_1_b, t2, 8320, 16, 16);
    // inverse rfft2 (combine65 + Hermitian extension fused into loader)
    k_rmul64<3><<<gt, bt, 0, stream>>>(IFm, nullptr, nullptr, t1, t2, bufA, 0, 0, 0);
    k_lmul64<3><<<gt, bt, 0, stream>>>(IFm, bufA, cat, nullptr, 32);

    // x_0o -> cat ch 0..15
    k_conv<16,16,4><<<dim3(64,4), 256, 0, stream>>>(x1, conv_0_w, conv_0_b, cat, 48, 0, 48, 0);

    // final 1x1 conv (48 -> 192)
    k_conv<48,192,2><<<dim3(128,4), 256, 0, stream>>>(cat, conv2_w, nullptr, outp, 48, 0, 192, 0);
}

// Round 5
// 508.459 us; speedup vs baseline: 3.9590x; 1.1552x over previous
//
#include <hip/hip_runtime.h>
#include <math.h>

#define PI_D 3.14159265358979323846
#define TWO_PI_F 6.2831853071795864f

// ---------------- persistent device buffers ---------------------------------
__device__ __align__(16) float2  g_Mf [128*128];
__device__ __align__(16) float2  g_Mb [128*128];
__device__ __align__(16) float2  g_F  [128*128];
__device__ __align__(16) float2  g_IF [128*128];
__device__ __align__(16) float   g_x1 [4*48*16384];
__device__ __align__(16) float2  g_bufA[64*16384];
__device__ __align__(16) float   g_mag[64*16384];
__device__ __align__(16) float   g_pha[64*16384];
__device__ __align__(16) float   g_t1 [64*16384];
__device__ __align__(16) float   g_t2 [64*16384];
__device__ __align__(16) float   g_cat[4*48*16384];

// ---------------- matrix builders -------------------------------------------
__global__ void k_build_M05f() {
    int tid = blockIdx.x*blockDim.x + threadIdx.x;
    if (tid >= 128*128) return;
    int o = tid >> 7, m = tid & 127;
    const double chc = -PI_D/128.0 * tan(PI_D/8.0) * 0.25;
    const double c   =  PI_D/(512.0*sin(PI_D/4.0));
    const double inv2pi = 1.0/(2.0*PI_D);
    float sr, si;
    {   // q = 2m term (sinc = 1)
        int n1 = 2*m - 127, tt = 2*(o - m);
        double ang = chc*(double)(n1*n1) + c*(double)(tt*tt);
        double r = ang*inv2pi; r -= floor(r);
        float af = (float)(r*2.0*PI_D);
        float sn, cs; __sincosf(af, &sn, &cs);
        sr = cs; si = sn;
    }
    for (int j = 0; j < 127; ++j) {
        int q  = 2*j + 1;
        int n1 = q - 127, tt = 2*o - q, d = q - 2*m;
        double ang = chc*(double)(n1*n1) + c*(double)(tt*tt);
        double r = ang*inv2pi; r -= floor(r);
        float af = (float)(r*2.0*PI_D);
        float s = (((d-1)>>1) & 1) ? -2.0f : 2.0f;
        s /= (3.14159265358979f*(float)d);
        float sn, cs; __sincosf(af, &sn, &cs);
        sr += s*cs; si += s*sn;
    }
    int n2 = 2*o - 127;
    double ph = chc*(double)(n2*n2) - PI_D/8.0;
    double r = ph*inv2pi; r -= floor(r);
    float pf = (float)(r*2.0*PI_D);
    float scale = (float)sqrt(c/PI_D);
    float sn, cs; __sincosf(pf, &sn, &cs);
    float cr = cs*scale, ci = sn*scale;
    g_Mf[tid] = make_float2(sr*cr - si*ci, sr*ci + si*cr);
}

__global__ void k_build_Mbf() {
    __shared__ float2 W[128];
    int t = threadIdx.x;
    for (int i = t; i < 128; i += 64) {
        float ang = TWO_PI_F*(float)i/128.0f;
        float sn, cs; sincosf(ang, &sn, &cs);
        float invs = 0.08838834764831845f;
        W[i] = make_float2(cs*invs, sn*invs);
    }
    __syncthreads();
    int tid = blockIdx.x*blockDim.x + t;
    if (tid >= 128*128) return;
    int o = tid >> 7, m = tid & 127;
    float sr = 0.f, si = 0.f;
    for (int r = 0; r < 128; ++r) {
        float2 a = g_Mf[(o<<7) + r];
        int k = ((r+64)*(m+64)) & 127;
        float2 w = W[k];
        sr += a.x*w.x - a.y*w.y;
        si += a.x*w.y + a.y*w.x;
    }
    g_Mb[tid] = make_float2(sr, si);
}

__global__ void k_build_Ff() {
    int tid = blockIdx.x*blockDim.x + threadIdx.x;
    if (tid >= 128*128) return;
    int k = tid >> 7, n = tid & 127;
    int p = (k*n) & 127;
    float ang = TWO_PI_F*(float)p/128.0f;
    float sn, cs; sincosf(ang, &sn, &cs);
    g_F[tid]  = make_float2(cs, -sn);
    g_IF[tid] = make_float2(cs*0.0078125f, sn*0.0078125f);
}

// ---------------- transform GEMMs: 64x64 tile, 512 thr, 4x2 micro -----------
// Loader modes: 0 complex natural  1 real from x1 slice
// 2 mag/pha full (fused combine)   3 mag/pha packed65 + Hermitian
template<int LM>
__device__ inline void load_T4(float2* tr, const float* mp, const float* pp,
                               const float2* Tc, const float* Trl,
                               int hh, int w4) {
    if (LM == 0) {
        const float4* src = (const float4*)(Tc + (hh<<7) + w4);
        float4 a = src[0], b = src[1];
        tr[0] = make_float2(a.x, a.y); tr[1] = make_float2(a.z, a.w);
        tr[2] = make_float2(b.x, b.y); tr[3] = make_float2(b.z, b.w);
    } else if (LM == 1) {
        float4 v = *(const float4*)(Trl + (hh<<7) + w4);
        tr[0] = make_float2(v.x, 0.f); tr[1] = make_float2(v.y, 0.f);
        tr[2] = make_float2(v.z, 0.f); tr[3] = make_float2(v.w, 0.f);
    } else if (LM == 2) {
#pragma unroll
        for (int i = 0; i < 4; ++i) {
            int idx = (hh<<7) + w4 + i;
            float m = mp[idx], ph = pp[idx];
            float sn, cs; __sincosf(ph, &sn, &cs);
            tr[i] = make_float2(m*cs, m*sn);
        }
    } else {
#pragma unroll
        for (int i = 0; i < 4; ++i) {
            int w = w4 + i;
            int h2 = hh, w2 = w; float sg = 1.f;
            if (w >= 65) { h2 = (128 - hh) & 127; w2 = 128 - w; sg = -1.f; }
            int idx = h2*65 + w2;
            float m = mp[idx], ph = pp[idx];
            float sn, cs; __sincosf(ph, &sn, &cs);
            tr[i] = make_float2(m*cs, sg*m*sn);
        }
    }
}

// out[p,h,j] = sum_w T[p,h,w] * A[j,w]
template<int LM>
__global__ __launch_bounds__(512, 1)
void k_rmul64(const float2* __restrict__ A, const float2* __restrict__ Tc,
              const float* __restrict__ Trl, const float* __restrict__ mp_,
              const float* __restrict__ pp_, float2* __restrict__ out,
              int Ctot, int Csub, int cstart) {
    __shared__ float2 Ts[64][33];   // [h][k]
    __shared__ float2 As[64][33];   // [j][k]
    int p  = blockIdx.z;
    int h0 = blockIdx.y << 6, j0 = blockIdx.x << 6;
    int t  = threadIdx.x;
    int tx = t & 31, ty = t >> 5;          // compute map: m=4ty+i, n=tx,tx+32
    int lr = t >> 3, l4 = (t & 7) * 4;     // staging: row lr, 4 elems at l4
    const float2* Tcp = nullptr; const float* Trp = nullptr;
    const float* mp = nullptr; const float* pp = nullptr;
    if (LM == 0) Tcp = Tc + ((long)p << 14);
    if (LM == 1) { int n = p / Csub, c = p - n*Csub; Trp = Trl + ((long)(n*Ctot + cstart + c) << 14); }
    if (LM == 2) { mp = mp_ + ((long)p << 14); pp = pp_ + ((long)p << 14); }
    if (LM == 3) { mp = mp_ + (long)p*8320;   pp = pp_ + (long)p*8320; }
    float2 acc[4][2] = {};
    for (int kc = 0; kc < 128; kc += 32) {
        __syncthreads();
        {
            float2 tr4[4];
            load_T4<LM>(tr4, mp, pp, Tcp, Trp, h0 + lr, kc + l4);
#pragma unroll
            for (int i = 0; i < 4; ++i) Ts[lr][l4 + i] = tr4[i];
            const float4* sA = (const float4*)(A + ((j0 + lr) << 7) + kc + l4);
            float4 a0 = sA[0], a1 = sA[1];
            As[lr][l4 + 0] = make_float2(a0.x, a0.y);
            As[lr][l4 + 1] = make_float2(a0.z, a0.w);
            As[lr][l4 + 2] = make_float2(a1.x, a1.y);
            As[lr][l4 + 3] = make_float2(a1.z, a1.w);
        }
        __syncthreads();
#pragma unroll
        for (int kk = 0; kk < 32; ++kk) {
            float2 av[4], bv[2];
#pragma unroll
            for (int i = 0; i < 4; ++i) av[i] = Ts[4*ty + i][kk];
            bv[0] = As[tx][kk]; bv[1] = As[tx + 32][kk];
#pragma unroll
            for (int i = 0; i < 4; ++i)
#pragma unroll
                for (int j = 0; j < 2; ++j) {
                    acc[i][j].x += av[i].x*bv[j].x - av[i].y*bv[j].y;
                    acc[i][j].y += av[i].x*bv[j].y + av[i].y*bv[j].x;
                }
        }
    }
    long base = ((long)p << 14);
#pragma unroll
    for (int i = 0; i < 4; ++i) {
        out[base + ((h0 + 4*ty + i) << 7) + j0 + tx]      = acc[i][0];
        out[base + ((h0 + 4*ty + i) << 7) + j0 + tx + 32] = acc[i][1];
    }
}

// out[p,j,w] = sum_h A[j,h] * T[p,h,w]; fused epilogues:
// EPI 1: mag/pha full -> o1,o2   2: abs->cat+coff   3: real-only->cat+coff
// EPI 4: mag/pha packed w<65 -> o1,o2
template<int EPI>
__global__ __launch_bounds__(512, 1)
void k_lmul64(const float2* __restrict__ A, const float2* __restrict__ in,
              float* __restrict__ o1, float* __restrict__ o2, int coff) {
    __shared__ float2 As[64][33];   // [j][k]
    __shared__ float2 Ts[32][66];   // [k][w]
    int p  = blockIdx.z;
    int j0 = blockIdx.y << 6, w0 = blockIdx.x << 6;
    int t  = threadIdx.x;
    int tx = t & 31, ty = t >> 5;
    int alr = t >> 3, al4 = (t & 7) * 4;   // As staging
    int tkr = t >> 4, tl4 = (t & 15) * 4;  // Ts staging
    const float2* T = in + ((long)p << 14);
    float2 acc[4][2] = {};
    for (int kc = 0; kc < 128; kc += 32) {
        __syncthreads();
        {
            const float4* sA = (const float4*)(A + ((j0 + alr) << 7) + kc + al4);
            float4 a0 = sA[0], a1 = sA[1];
            As[alr][al4 + 0] = make_float2(a0.x, a0.y);
            As[alr][al4 + 1] = make_float2(a0.z, a0.w);
            As[alr][al4 + 2] = make_float2(a1.x, a1.y);
            As[alr][al4 + 3] = make_float2(a1.z, a1.w);
            const float4* sT = (const float4*)(T + ((kc + tkr) << 7) + w0 + tl4);
            float4* dT = (float4*)&Ts[tkr][tl4];
            dT[0] = sT[0]; dT[1] = sT[1];
        }
        __syncthreads();
#pragma unroll
        for (int kk = 0; kk < 32; ++kk) {
            float2 av[4], bv[2];
#pragma unroll
            for (int i = 0; i < 4; ++i) av[i] = As[4*ty + i][kk];
            bv[0] = Ts[kk][tx]; bv[1] = Ts[kk][tx + 32];
#pragma unroll
            for (int i = 0; i < 4; ++i)
#pragma unroll
                for (int j = 0; j < 2; ++j) {
                    if (EPI == 3) {
                        acc[i][j].x += av[i].x*bv[j].x - av[i].y*bv[j].y;
                    } else {
                        acc[i][j].x += av[i].x*bv[j].x - av[i].y*bv[j].y;
                        acc[i][j].y += av[i].x*bv[j].y + av[i].y*bv[j].x;
                    }
                }
        }
    }
#pragma unroll
    for (int i = 0; i < 4; ++i) {
#pragma unroll
        for (int j = 0; j < 2; ++j) {
            int jj = j0 + 4*ty + i;
            int ww = w0 + tx + 32*j;
            float2 v = acc[i][j];
            if (EPI == 1) {
                long idx = ((long)p << 14) + (jj << 7) + ww;
                o1[idx] = sqrtf(v.x*v.x + v.y*v.y);
                o2[idx] = atan2f(v.y, v.x);
            } else if (EPI == 2) {
                int n = p >> 4, c = p & 15;
                o1[((long)(n*48 + coff + c) << 14) + (jj << 7) + ww] = sqrtf(v.x*v.x + v.y*v.y);
            } else if (EPI == 3) {
                int n = p >> 4, c = p & 15;
                o1[((long)(n*48 + coff + c) << 14) + (jj << 7) + ww] = v.x;
            } else if (EPI == 4) {
                if (ww < 65) {
                    long idx = (long)p*8320 + jj*65 + ww;
                    o1[idx] = sqrtf(v.x*v.x + v.y*v.y);
                    o2[idx] = atan2f(v.y, v.x);
                }
            }
        }
    }
}

// ---------------- 1x1 conv --------------------------------------------------
template<int CIN, int COUT, int VEC>
__global__ __launch_bounds__(256, 1)
void k_conv(const float* __restrict__ in, const float* __restrict__ wgt,
            const float* __restrict__ bias, float* __restrict__ out,
            int Ctin, int cstart, int Ctout, int costart) {
    const int S = 16384;
    const int STILE = 64*VEC;
    const int OW = COUT/4;
    __shared__ float xs[8][STILE];
    int n  = blockIdx.y;
    int s0 = blockIdx.x * STILE;
    int t  = threadIdx.x, lane = t & 63;
    int wid = __builtin_amdgcn_readfirstlane(t >> 6);
    const float* wb  = wgt + wid*OW*CIN;
    const float* inb = in + ((long)(n*Ctin + cstart))*S + s0;
    float acc[OW][VEC] = {};
    for (int c0 = 0; c0 < CIN; c0 += 8) {
        __syncthreads();
        if (VEC == 4) {
            *(float4*)&xs[t>>6][(t&63)*4]     = *(const float4*)(inb + (long)(c0 + (t>>6))*S + (t&63)*4);
            *(float4*)&xs[(t>>6)+4][(t&63)*4] = *(const float4*)(inb + (long)(c0+4 + (t>>6))*S + (t&63)*4);
        } else {
            *(float4*)&xs[t>>5][(t&31)*4]     = *(const float4*)(inb + (long)(c0 + (t>>5))*S + (t&31)*4);
        }
        __syncthreads();
#pragma unroll
        for (int cc = 0; cc < 8; ++cc) {
            float xv[VEC];
#pragma unroll
            for (int v = 0; v < VEC; ++v) xv[v] = xs[cc][lane*VEC + v];
#pragma unroll
            for (int j = 0; j < OW; ++j) {
                float wv = wb[j*CIN + c0 + cc];
#pragma unroll
                for (int v = 0; v < VEC; ++v) acc[j][v] += wv*xv[v];
            }
        }
    }
#pragma unroll
    for (int j = 0; j < OW; ++j) {
        int o = wid*OW + j;
        float bvv = bias ? bias[o] : 0.f;
        float* op = out + ((long)(n*Ctout + costart + o))*S + s0 + lane*VEC;
        if (VEC == 4) {
            *(float4*)op = make_float4(acc[j][0]+bvv, acc[j][1]+bvv, acc[j][2]+bvv, acc[j][3]+bvv);
        } else {
            *(float2*)op = make_float2(acc[j][0]+bvv, acc[j][1]+bvv);
        }
    }
}

// ---------------- old conv (packed S=8320 arrays) ---------------------------
template<int CIN, int COUT>
__global__ __launch_bounds__(256, 1)
void k_conv1x1t(const float* __restrict__ in, const float* __restrict__ w,
                const float* __restrict__ b, float* __restrict__ out,
                int S, int Ctot_in, int Ctot_out) {
    __shared__ float xs[4][64];
    __shared__ float ws[4][COUT];
    int n  = blockIdx.y;
    int s0 = blockIdx.x * 64;
    int t  = threadIdx.x;
    int sl = t & 63;
    int og = t >> 6;
    const int NO = COUT/4;
    float acc[NO];
#pragma unroll
    for (int j = 0; j < NO; ++j) acc[j] = 0.f;
    const float* inb = in + (long)n*Ctot_in*S + s0;
    for (int c0 = 0; c0 < CIN; c0 += 4) {
        xs[og][sl] = inb[(long)(c0+og)*S + sl];
        for (int i = t; i < 4*COUT; i += 256) {
            int cc = i / COUT, oo = i - cc*COUT;
            ws[cc][oo] = w[oo*CIN + c0 + cc];
        }
        __syncthreads();
#pragma unroll
        for (int cc = 0; cc < 4; ++cc) {
            float xv = xs[cc][sl];
#pragma unroll
            for (int j = 0; j < NO; ++j)
                acc[j] += ws[cc][og + 4*j] * xv;
        }
        __syncthreads();
    }
#pragma unroll
    for (int j = 0; j < NO; ++j) {
        int o = og + 4*j;
        float v = acc[j] + (b ? b[o] : 0.f);
        out[((long)n*Ctot_out + o)*S + s0 + sl] = v;
    }
}

// ---------------- maskconv: LDS-tiled, branchless 3x3 -----------------------
__global__ __launch_bounds__(256, 2)
void k_maskconv2(const float* __restrict__ mag, const float* __restrict__ ws3,
                 const float* __restrict__ bs, const float* __restrict__ wf,
                 const float* __restrict__ bf, float* __restrict__ out) {
    __shared__ float patch[16][324];   // 18x18 per channel, mask1 applied
    int n = blockIdx.y;
    int h0 = (blockIdx.x >> 3) << 4, w0 = (blockIdx.x & 7) << 4;
    int t = threadIdx.x;
    const float* magn = mag + ((long)n << 18);   // n*16*16384
    for (int idx = t; idx < 16*324; idx += 256) {
        int c = idx / 324, r = idx - c*324;
        int ph = r / 18, pw = r - ph*18;
        int gh = h0 - 1 + ph, gw = w0 - 1 + pw;
        float v = 0.f;
        if (gh >= 19 && gh < 109 && gw >= 19 && gw < 109)
            v = magn[(c<<14) + (gh<<7) + gw];
        patch[c][r] = v;
    }
    __syncthreads();
    int ty = t >> 4, tx = t & 15;
    int h = h0 + ty, w = w0 + tx;
    bool in1 = (h >= 19 && h < 109 && w >= 19 && w < 109);
    unsigned long long bal = __ballot(in1);
    float res[16];
    if (bal != 0ull) {
        float acc[16];
#pragma unroll
        for (int o = 0; o < 16; ++o) acc[o] = bs[o];
        for (int c = 0; c < 16; ++c) {
            float tap[9];
#pragma unroll
            for (int dh = 0; dh < 3; ++dh)
#pragma unroll
                for (int dw = 0; dw < 3; ++dw)
                    tap[dh*3+dw] = patch[c][(ty+dh)*18 + tx+dw];
            const float* wp = ws3 + c*9;   // + o*144 + k
#pragma unroll
            for (int o = 0; o < 16; ++o)
#pragma unroll
                for (int k = 0; k < 9; ++k)
                    acc[o] = fmaf(wp[o*144 + k], tap[k], acc[o]);
        }
#pragma unroll
        for (int o = 0; o < 16; ++o) res[o] = acc[o];
    }
    if (bal != ~0ull) {
        float xv[16];
#pragma unroll
        for (int c = 0; c < 16; ++c) xv[c] = magn[(c<<14) + (h<<7) + w];
#pragma unroll
        for (int o = 0; o < 16; ++o) {
            float a = bf[o];
#pragma unroll
            for (int c = 0; c < 16; ++c) a = fmaf(wf[o*16 + c], xv[c], a);
            if (!in1) res[o] = a;
        }
    }
#pragma unroll
    for (int o = 0; o < 16; ++o)
        out[((long)((n<<4) + o) << 14) + (h << 7) + w] = res[o];
}

// ---------------- launch ----------------------------------------------------
extern "C" void kernel_launch(void* const* d_in, const int* in_sizes, int n_in,
                              void* d_out, int out_size, void* d_ws, size_t ws_size,
                              hipStream_t stream) {
    (void)in_sizes; (void)n_in; (void)out_size; (void)d_ws; (void)ws_size;
    const float* x        = (const float*)d_in[0];
    const float* conv1_w  = (const float*)d_in[1];
    const float* mag_s_w  = (const float*)d_in[2];
    const float* mag_s_b  = (const float*)d_in[3];
    const float* mag_f_w  = (const float*)d_in[4];
    const float* mag_f_b  = (const float*)d_in[5];
    const float* mag_w_   = (const float*)d_in[6];
    const float* mag_b_   = (const float*)d_in[7];
    const float* pha_w_   = (const float*)d_in[8];
    const float* pha_b_   = (const float*)d_in[9];
    const float* conv_0_w = (const float*)d_in[10];
    const float* conv_0_b = (const float*)d_in[11];
    const float* conv_1_w = (const float*)d_in[12];
    const float* conv_1_b = (const float*)d_in[13];
    const float* conv2_w  = (const float*)d_in[14];
    float* outp = (float*)d_out;

    float2 *Mf, *Mb, *Fm, *IFm, *bufA;
    float *x1, *mag, *pha, *t1, *t2, *cat;
    hipGetSymbolAddress((void**)&Mf,   HIP_SYMBOL(g_Mf));
    hipGetSymbolAddress((void**)&Mb,   HIP_SYMBOL(g_Mb));
    hipGetSymbolAddress((void**)&Fm,   HIP_SYMBOL(g_F));
    hipGetSymbolAddress((void**)&IFm,  HIP_SYMBOL(g_IF));
    hipGetSymbolAddress((void**)&bufA, HIP_SYMBOL(g_bufA));
    hipGetSymbolAddress((void**)&x1,   HIP_SYMBOL(g_x1));
    hipGetSymbolAddress((void**)&mag,  HIP_SYMBOL(g_mag));
    hipGetSymbolAddress((void**)&pha,  HIP_SYMBOL(g_pha));
    hipGetSymbolAddress((void**)&t1,   HIP_SYMBOL(g_t1));
    hipGetSymbolAddress((void**)&t2,   HIP_SYMBOL(g_t2));
    hipGetSymbolAddress((void**)&cat,  HIP_SYMBOL(g_cat));

    dim3 gt(2,2,64), bt(512,1,1);

    // matrices
    k_build_M05f<<<256, 64, 0, stream>>>();
    k_build_Mbf <<<256, 64, 0, stream>>>();
    k_build_Ff  <<<256, 64, 0, stream>>>();

    // x1 = 1x1 conv (192 -> 48)
    k_conv<192,48,4><<<dim3(64,4), 256, 0, stream>>>(x, conv1_w, nullptr, x1, 192, 0, 48, 0);

    // FRFT forward on x_05 (ch 16..31): Fre = Mf X Mf^T; fused mag/pha
    k_rmul64<1><<<gt, bt, 0, stream>>>(Mf, nullptr, x1, nullptr, nullptr, bufA, 48, 16, 16);
    k_lmul64<1><<<gt, bt, 0, stream>>>(Mf, bufA, mag, pha, 0);

    // masked convs + channel mixes
    k_maskconv2<<<dim3(64,4), 256, 0, stream>>>(mag, mag_s_w, mag_s_b, mag_f_w, mag_f_b, t1);
    k_conv<16,16,4><<<dim3(64,4), 256, 0, stream>>>(t1,  mag_w_, mag_b_, t2, 16, 0, 16, 0);
    k_conv<16,16,4><<<dim3(64,4), 256, 0, stream>>>(pha, pha_w_, pha_b_, t1, 16, 0, 16, 0);

    // FRFT backward (combine fused into loader): |Mb Y Mb^T| -> cat ch 16..31
    k_rmul64<2><<<gt, bt, 0, stream>>>(Mb, nullptr, nullptr, t2, t1, bufA, 0, 0, 0);
    k_lmul64<2><<<gt, bt, 0, stream>>>(Mb, bufA, cat, nullptr, 16);

    // FFT branch on x_1 (ch 32..47): G = F X F^T; fused packed mag/pha
    k_rmul64<1><<<gt, bt, 0, stream>>>(Fm, nullptr, x1, nullptr, nullptr, bufA, 48, 16, 32);
    k_lmul64<4><<<gt, bt, 0, stream>>>(Fm, bufA, mag, pha, 0);
    k_conv1x1t<16,16><<<dim3(130,4), 256, 0, stream>>>(mag, conv_1_w, conv_1_b, t1, 8320, 16, 16);
    k_conv1x1t<16,16><<<dim3(130,4), 256, 0, stream>>>(pha, conv_1_w, conv_1_b, t2, 8320, 16, 16);
    // inverse rfft2 (combine65 + Hermitian extension fused into loader)
    k_rmul64<3><<<gt, bt, 0, stream>>>(IFm, nullptr, nullptr, t1, t2, bufA, 0, 0, 0);
    k_lmul64<3><<<gt, bt, 0, stream>>>(IFm, bufA, cat, nullptr, 32);

    // x_0o -> cat ch 0..15
    k_conv<16,16,4><<<dim3(64,4), 256, 0, stream>>>(x1, conv_0_w, conv_0_b, cat, 48, 0, 48, 0);

    // final 1x1 conv (48 -> 192)
    k_conv<48,192,2><<<dim3(128,4), 256, 0, stream>>>(cat, conv2_w, nullptr, outp, 48, 0, 192, 0);
}